// Round 19
// baseline (365.658 us; speedup 1.0000x reference)
//
#include <hip/hip_runtime.h>
#include <cstdint>

// TGN memory update — round 19: max-TLP GEMM. M=16/block, 512 thr, acc=24,
// launch_bounds(512,6) -> 3 blocks/CU (24 waves). gh merged into gi steps
// 0-3 (16 steps). No prefetch ring — TLP hides latency. Fused gather (R18).

#define MEMD 128
#define ACCD 384
#define MSGD 512

typedef __attribute__((ext_vector_type(8))) short bf16x8;
typedef __attribute__((ext_vector_type(2))) short bf16x2;
typedef __attribute__((ext_vector_type(4))) float f32x4;

static __device__ __forceinline__ short f2bf(float f) {
    uint32_t u = __builtin_bit_cast(uint32_t, f);
    u = (u + 0x7FFFu + ((u >> 16) & 1u)) >> 16;
    return (short)u;
}
static __device__ __forceinline__ float bf2f(short s) {
    return __builtin_bit_cast(float, ((uint32_t)(uint16_t)s) << 16);
}
static __device__ __forceinline__ uint32_t pack2bf(float a, float b) {
    return (uint32_t)(uint16_t)f2bf(a) | ((uint32_t)(uint16_t)f2bf(b) << 16);
}

// ---------------- Prep B: weights f32 -> bf16 frag-major ----------------
#define GI_SLOTS (24 * 16 * 64)
#define GH_SLOTS (24 * 4 * 64)

__global__ __launch_bounds__(256) void tgn_prep_w(
    const float* __restrict__ W_ih, const float* __restrict__ W_hh,
    bf16x8* __restrict__ Wb)
{
    const int s = blockIdx.x * 256 + threadIdx.x;
    if (s >= GI_SLOTS + GH_SLOTS) return;
    const float* src;
    if (s < GI_SLOTS) {
        const int n = s / (16 * 64), rem = s % (16 * 64);
        const int ks = rem / 64, l = rem % 64;
        const int j = n * 16 + (l & 15), k = ks * 32 + (l >> 4) * 8;
        src = W_ih + (size_t)j * MSGD + k;
    } else {
        const int s2 = s - GI_SLOTS;
        const int n = s2 / (4 * 64), rem = s2 % (4 * 64);
        const int ks = rem / 64, l = rem % 64;
        const int j = n * 16 + (l & 15), k = ks * 32 + (l >> 4) * 8;
        src = W_hh + (size_t)j * MEMD + k;
    }
    bf16x8 v;
    #pragma unroll
    for (int e = 0; e < 8; ++e) v[e] = f2bf(src[e]);
    Wb[s] = v;
}

// ---------------- Phase 1: build per-node linked lists ----------------
__global__ __launch_bounds__(256) void tgn_fill(
    const int* __restrict__ src, const int* __restrict__ dst, const int* __restrict__ t,
    int* __restrict__ head, int* __restrict__ nxt, int* __restrict__ lu_new,
    int n_events)
{
    const int e = blockIdx.x * 256 + threadIdx.x;
    if (e >= n_events) return;
    const int s = src[e];
    const int d = dst[e];
    const int te = t[e];
    nxt[2 * e]     = atomicExch(head + s, 2 * e);
    nxt[2 * e + 1] = atomicExch(head + d, 2 * e + 1);
    atomicMax(lu_new + s, te);
    atomicMax(lu_new + d, te);
}

// ---------------- Phase 2: fused gather + MFMA GEMM + GRU ----------------
// 512 threads (8 waves), 16 nodes/block, 16 KB LDS, 3 blocks/CU.
// Wave wv: gathers nodes {2wv, 2wv+1}, owns N-tiles {wv, wv+8, wv+16}.
__global__ __launch_bounds__(512, 6) void tgn_gru_fused(
    const float* __restrict__ mem, const int* __restrict__ head,
    const int* __restrict__ nxt,
    const int* __restrict__ src, const int* __restrict__ dst,
    const int* __restrict__ t, const float* __restrict__ raw_msg,
    const int* __restrict__ last_update,
    const float* __restrict__ time_w, const float* __restrict__ time_b,
    const bf16x8* __restrict__ Wb,
    const float* __restrict__ b_ih, const float* __restrict__ b_hh,
    const int* __restrict__ lu, float* __restrict__ out,
    float* __restrict__ out2, int n_nodes)
{
    __shared__ bf16x8 Xf[16 * 64];          // 16 KB : X tile (frag-major, 1 M-frag)
    ushort* Xh = reinterpret_cast<ushort*>(Xf);
    uint32_t* X32 = reinterpret_cast<uint32_t*>(Xf);
    float*  Sout = reinterpret_cast<float*>(Xf);   // 8 KB, reused after mv reads

    const int tid = threadIdx.x;
    const int lane = tid & 63;
    const int wv = tid >> 6;                 // wave id 0..7 (uniform)
    const int node0 = blockIdx.x * 16;

    const bf16x8* __restrict__ Wh = Wb + GI_SLOTS;
    const int n0 = wv, n1 = wv + 8, n2 = wv + 16;

    // ---- stage mem part of X (ks 0..3): direct f32 read + convert ----
    // slots 0..1023; thread stages 2.
    #pragma unroll
    for (int i = 0; i < 2; ++i) {
        const int slot = i * 512 + tid;
        const int l = slot & 63;
        const int ks = (slot >> 6) & 15;
        if (ks < 4) {
            int node = node0 + (l & 15);
            if (node >= n_nodes) node = n_nodes - 1;
            const int kbase = ks * 32 + (l >> 4) * 8;
            const float4 pa = *reinterpret_cast<const float4*>(mem + (size_t)node * MEMD + kbase);
            const float4 pb = *reinterpret_cast<const float4*>(mem + (size_t)node * MEMD + kbase + 4);
            bf16x8 xv;
            xv[0] = f2bf(pa.x); xv[1] = f2bf(pa.y); xv[2] = f2bf(pa.z); xv[3] = f2bf(pa.w);
            xv[4] = f2bf(pb.x); xv[5] = f2bf(pb.y); xv[6] = f2bf(pb.z); xv[7] = f2bf(pb.w);
            Xf[slot] = xv;
        }
    }

    const int col = lane & 15;
    const int rgrp = lane >> 4;

    // hmask early (4 nodes per thread-row-group)
    uint32_t hmask = 0;
    #pragma unroll
    for (int r = 0; r < 4; ++r) {
        const int node = node0 + rgrp * 4 + r;
        if (node < n_nodes && head[node] >= 0) hmask |= 1u << r;
    }

    // ---- gather: 2 independent chains interleaved ----
    {
        const int j0 = lane * 2;
        const float2 tw = *reinterpret_cast<const float2*>(time_w + j0);
        const float2 tb = *reinterpret_cast<const float2*>(time_b + j0);
        const int nb = node0 + wv * 2;

        int kq[2];
        float lus[2];
        float A[2][6];
        int C[2];
        #pragma unroll
        for (int q = 0; q < 2; ++q) {
            kq[q] = (nb + q < n_nodes) ? head[nb + q] : -1;
            lus[q] = 0.f;
            C[q] = 0;
            #pragma unroll
            for (int z = 0; z < 6; ++z) A[q][z] = 0.f;
        }
        #pragma unroll
        for (int q = 0; q < 2; ++q)
            if (kq[q] >= 0) lus[q] = (float)last_update[nb + q];

        bool more = (kq[0] >= 0) | (kq[1] >= 0);
        while (more) {
            #pragma unroll
            for (int q = 0; q < 2; ++q) {
                const int k = kq[q];
                if (k >= 0) {
                    kq[q] = nxt[k];
                    const int e = k >> 1;
                    const int other = (k & 1) ? src[e] : dst[e];
                    const float te = (float)t[e];
                    const float2 rw = *reinterpret_cast<const float2*>(raw_msg + (size_t)e * MEMD + j0);
                    const float2 mb = *reinterpret_cast<const float2*>(mem + (size_t)other * MEMD + j0);
                    const float dt = te - lus[q];
                    A[q][4] += __cosf(fmaf(dt, tw.x, tb.x));
                    A[q][5] += __cosf(fmaf(dt, tw.y, tb.y));
                    A[q][2] += rw.x; A[q][3] += rw.y;
                    A[q][0] += mb.x; A[q][1] += mb.y;
                    ++C[q];
                }
            }
            more = (kq[0] >= 0) | (kq[1] >= 0);
        }

        #pragma unroll
        for (int q = 0; q < 2; ++q) {
            if (C[q] > 0) {
                const float inv = 1.0f / (float)C[q];
                const int nif = wv * 2 + q;              // node in tile 0..15
                #pragma unroll
                for (int p = 0; p < 3; ++p) {
                    const int cc = 128 + p * 128 + j0;   // X column of dim pair
                    const int ks = cc >> 5;
                    const int hi = (cc >> 3) & 3;
                    const int u32idx = (ks * 64 + hi * 16 + nif) * 4 + (lane & 3);
                    X32[u32idx] = pack2bf(A[q][p * 2] * inv, A[q][p * 2 + 1] * inv);
                }
            }
        }
    }

    __syncthreads();   // X fully assembled; waves run free from here

    f32x4 acc_i[3], acc_h[3];
    #pragma unroll
    for (int c = 0; c < 3; ++c) {
        acc_i[c] = (f32x4){0.f, 0.f, 0.f, 0.f};
        acc_h[c] = (f32x4){0.f, 0.f, 0.f, 0.f};
    }

    // ---- merged steps 0..3: gh + gi share the A-frag ----
    #pragma unroll
    for (int ks = 0; ks < 4; ++ks) {
        const bf16x8 bh0 = Wh[(size_t)(n0 * 4 + ks) * 64 + lane];
        const bf16x8 bh1 = Wh[(size_t)(n1 * 4 + ks) * 64 + lane];
        const bf16x8 bh2 = Wh[(size_t)(n2 * 4 + ks) * 64 + lane];
        const bf16x8 bi0 = Wb[(size_t)(n0 * 16 + ks) * 64 + lane];
        const bf16x8 bi1 = Wb[(size_t)(n1 * 16 + ks) * 64 + lane];
        const bf16x8 bi2 = Wb[(size_t)(n2 * 16 + ks) * 64 + lane];
        const bf16x8 a0 = Xf[ks * 64 + lane];
        acc_h[0] = __builtin_amdgcn_mfma_f32_16x16x32_bf16(a0, bh0, acc_h[0], 0, 0, 0);
        acc_h[1] = __builtin_amdgcn_mfma_f32_16x16x32_bf16(a0, bh1, acc_h[1], 0, 0, 0);
        acc_h[2] = __builtin_amdgcn_mfma_f32_16x16x32_bf16(a0, bh2, acc_h[2], 0, 0, 0);
        acc_i[0] = __builtin_amdgcn_mfma_f32_16x16x32_bf16(a0, bi0, acc_i[0], 0, 0, 0);
        acc_i[1] = __builtin_amdgcn_mfma_f32_16x16x32_bf16(a0, bi1, acc_i[1], 0, 0, 0);
        acc_i[2] = __builtin_amdgcn_mfma_f32_16x16x32_bf16(a0, bi2, acc_i[2], 0, 0, 0);
    }
    // ---- steps 4..15: gi only ----
    #pragma unroll
    for (int ks = 4; ks < 16; ++ks) {
        const bf16x8 bi0 = Wb[(size_t)(n0 * 16 + ks) * 64 + lane];
        const bf16x8 bi1 = Wb[(size_t)(n1 * 16 + ks) * 64 + lane];
        const bf16x8 bi2 = Wb[(size_t)(n2 * 16 + ks) * 64 + lane];
        const bf16x8 a0 = Xf[ks * 64 + lane];
        acc_i[0] = __builtin_amdgcn_mfma_f32_16x16x32_bf16(a0, bi0, acc_i[0], 0, 0, 0);
        acc_i[1] = __builtin_amdgcn_mfma_f32_16x16x32_bf16(a0, bi1, acc_i[1], 0, 0, 0);
        acc_i[2] = __builtin_amdgcn_mfma_f32_16x16x32_bf16(a0, bi2, acc_i[2], 0, 0, 0);
    }

    // ---- GRU epilogue: wave-local triple (j, j+128, j+256) ----
    const int jr = wv * 16 + col;            // 0..127
    const float bir = b_ih[jr], biz = b_ih[jr + 128], bin = b_ih[jr + 256];
    const float bhr = b_hh[jr], bhz = b_hh[jr + 128], bhn = b_hh[jr + 256];
    const int ksj = jr >> 5;
    const int sub = ((jr >> 3) & 3) * 16;
    const int elem = jr & 7;

    float rout[4];
    #pragma unroll
    for (int r = 0; r < 4; ++r) {
        const bool has = (hmask >> r) & 1;
        const float gir = (has ? acc_i[0][r] : 0.f) + bir;
        const float giz = (has ? acc_i[1][r] : 0.f) + biz;
        const float gin = (has ? acc_i[2][r] : 0.f) + bin;
        const float ghr = acc_h[0][r] + bhr;
        const float ghz = acc_h[1][r] + bhz;
        const float ghn = acc_h[2][r] + bhn;
        const float rr = __fdividef(1.0f, 1.0f + __expf(-(gir + ghr)));
        const float zz = __fdividef(1.0f, 1.0f + __expf(-(giz + ghz)));
        const float targ = fmaf(rr, ghn, gin);
        const float e2v = __expf(2.0f * targ);
        const float nn = __fdividef(e2v - 1.0f, e2v + 1.0f);
        const int slot = ksj * 64 + sub + (rgrp * 4 + r);
        const float mv = bf2f((short)Xh[slot * 8 + elem]);
        rout[r] = (1.0f - zz) * nn + zz * mv;
    }
    // fused last_update output (16 values per block)
    if (tid < 16 && node0 + tid < n_nodes) out2[node0 + tid] = (float)lu[node0 + tid];
    __syncthreads();   // all waves done with Xf (mv) -> reuse as Sout

    #pragma unroll
    for (int r = 0; r < 4; ++r)
        Sout[(rgrp * 4 + r) * MEMD + jr] = rout[r];
    __syncthreads();

    // ---- fully-coalesced float4 write-out (16 nodes x 128 f32) ----
    float4* out4 = reinterpret_cast<float4*>(out + (size_t)node0 * MEMD);
    const float4* S4 = reinterpret_cast<const float4*>(Sout);
    if (node0 + 16 <= n_nodes) {
        out4[tid] = S4[tid];
    } else {
        if (node0 + (tid >> 5) < n_nodes) out4[tid] = S4[tid];
    }
}

extern "C" void kernel_launch(void* const* d_in, const int* in_sizes, int n_in,
                              void* d_out, int out_size, void* d_ws, size_t ws_size,
                              hipStream_t stream)
{
    const float* memory      = (const float*)d_in[0];
    const int*   last_update = (const int*)d_in[1];
    const int*   src         = (const int*)d_in[2];
    const int*   dst         = (const int*)d_in[3];
    const int*   t           = (const int*)d_in[4];
    const float* raw_msg     = (const float*)d_in[5];
    const float* time_w      = (const float*)d_in[6];
    const float* time_b      = (const float*)d_in[7];
    const float* W_ih        = (const float*)d_in[8];
    const float* W_hh        = (const float*)d_in[9];
    const float* b_ih        = (const float*)d_in[10];
    const float* b_hh        = (const float*)d_in[11];

    const int n_nodes  = in_sizes[0] / MEMD;
    const int n_events = in_sizes[2];

    // Workspace: head | next | lu | Wb
    int*   head = (int*)d_ws;
    int*   nxt  = head + n_nodes;
    int*   lu   = nxt + 2 * n_events;
    bf16x8* Wb  = (bf16x8*)(lu + n_nodes);

    (void)hipMemsetAsync(head, 0xFF, (size_t)n_nodes * sizeof(int), stream); // -1
    (void)hipMemsetAsync(lu, 0, (size_t)n_nodes * sizeof(int), stream);

    tgn_prep_w<<<dim3((GI_SLOTS + GH_SLOTS + 255) / 256), dim3(256), 0, stream>>>(W_ih, W_hh, Wb);

    tgn_fill<<<dim3((n_events + 255) / 256), dim3(256), 0, stream>>>(
        src, dst, t, head, nxt, lu, n_events);

    float* out2 = (float*)d_out + (size_t)n_nodes * MEMD;
    tgn_gru_fused<<<dim3((n_nodes + 15) / 16), dim3(512), 0, stream>>>(
        memory, head, nxt, src, dst, t, raw_msg, last_update, time_w, time_b,
        Wb, b_ih, b_hh, lu, (float*)d_out, out2, n_nodes);
}

// Round 20
// 321.370 us; speedup vs baseline: 1.1378x; 1.1378x over previous
//
#include <hip/hip_runtime.h>
#include <cstdint>

// TGN memory update — round 20: fp8 (OCP e4m3) GEMM operands. Halves the
// L2 weight stream at constant M=32 / 2 blocks/CU (the R18 optimum).
// X in LDS as fp8 + bf16 mirror of mem k-steps for the epilogue blend.
// Structure otherwise = R18 (fused gather, depth-3 reg ring, no loop barriers).

#define MEMD 128
#define ACCD 384
#define MSGD 512

typedef __attribute__((ext_vector_type(8))) short bf16x8;
typedef __attribute__((ext_vector_type(4))) float f32x4;

static __device__ __forceinline__ short f2bf(float f) {
    uint32_t u = __builtin_bit_cast(uint32_t, f);
    u = (u + 0x7FFFu + ((u >> 16) & 1u)) >> 16;
    return (short)u;
}
static __device__ __forceinline__ float bf2f(short s) {
    return __builtin_bit_cast(float, ((uint32_t)(uint16_t)s) << 16);
}
// f32 -> fp8 e4m3fn (OCP), RTNE, saturating
static __device__ __forceinline__ uint32_t f2fp8(float x) {
    float ax = fabsf(x);
    ax = fminf(ax, 448.0f);
    const uint32_t s = (__builtin_bit_cast(uint32_t, x) >> 31) << 7;
    const uint32_t b = __builtin_bit_cast(uint32_t, ax);
    int e = (int)((b >> 23) & 0xffu) - 127;
    const uint32_t m = b & 0x7fffffu;
    if (e < -6) {                       // subnormal / zero
        const int m3 = (int)(ax * 512.0f + 0.5f);
        return s | (uint32_t)m3;        // m3==8 naturally encodes 2^-6
    }
    uint32_t m3 = (m + 0x7FFFFu + ((m >> 20) & 1u)) >> 20;
    if (m3 == 8u) { m3 = 0u; ++e; }
    if (e > 8) return s | 0x7Eu;        // clamp to 448
    return s | ((uint32_t)(e + 7) << 3) | m3;
}
static __device__ __forceinline__ long pack8fp8(const float* v) {
    uint32_t lo = f2fp8(v[0]) | (f2fp8(v[1]) << 8) | (f2fp8(v[2]) << 16) | (f2fp8(v[3]) << 24);
    uint32_t hi = f2fp8(v[4]) | (f2fp8(v[5]) << 8) | (f2fp8(v[6]) << 16) | (f2fp8(v[7]) << 24);
    return (long)(((uint64_t)hi << 32) | lo);
}

// ---------------- Prep B: weights f32 -> fp8 frag-major ----------------
#define GI_SLOTS (24 * 16 * 64)
#define GH_SLOTS (24 * 4 * 64)

__global__ __launch_bounds__(256) void tgn_prep_w(
    const float* __restrict__ W_ih, const float* __restrict__ W_hh,
    long* __restrict__ Wb)
{
    const int s = blockIdx.x * 256 + threadIdx.x;
    if (s >= GI_SLOTS + GH_SLOTS) return;
    const float* src;
    if (s < GI_SLOTS) {
        const int n = s / (16 * 64), rem = s % (16 * 64);
        const int ks = rem / 64, l = rem % 64;
        const int j = n * 16 + (l & 15), k = ks * 32 + (l >> 4) * 8;
        src = W_ih + (size_t)j * MSGD + k;
    } else {
        const int s2 = s - GI_SLOTS;
        const int n = s2 / (4 * 64), rem = s2 % (4 * 64);
        const int ks = rem / 64, l = rem % 64;
        const int j = n * 16 + (l & 15), k = ks * 32 + (l >> 4) * 8;
        src = W_hh + (size_t)j * MEMD + k;
    }
    float v[8];
    #pragma unroll
    for (int e = 0; e < 8; ++e) v[e] = src[e];
    Wb[s] = pack8fp8(v);
}

// ---------------- Phase 1: build per-node linked lists ----------------
__global__ __launch_bounds__(256) void tgn_fill(
    const int* __restrict__ src, const int* __restrict__ dst, const int* __restrict__ t,
    int* __restrict__ head, int* __restrict__ nxt, int* __restrict__ lu_new,
    int n_events)
{
    const int e = blockIdx.x * 256 + threadIdx.x;
    if (e >= n_events) return;
    const int s = src[e];
    const int d = dst[e];
    const int te = t[e];
    nxt[2 * e]     = atomicExch(head + s, 2 * e);
    nxt[2 * e + 1] = atomicExch(head + d, 2 * e + 1);
    atomicMax(lu_new + s, te);
    atomicMax(lu_new + d, te);
}

// ---------------- Phase 2: fused gather + fp8 MFMA GEMM + GRU -------------
// 512 threads (8 waves), 32 nodes/block. Wave wv: gathers nodes wv*4..+3
// (4 chains interleaved), owns N-tiles {wv, wv+8, wv+16}. Depth-3 reg ring.
#define WPTR(NN, S) ((S) < 4 ? (Wh + (size_t)((NN) * 4 + (S)) * 64 + lane)      \
                             : (Wb + (size_t)((NN) * 16 + (S) - 4) * 64 + lane))

#define MFMA2(ACCN, BV)                                                              \
    ACCN[0] = __builtin_amdgcn_mfma_f32_16x16x32_fp8_fp8(a0, BV, ACCN[0], 0, 0, 0);  \
    ACCN[1] = __builtin_amdgcn_mfma_f32_16x16x32_fp8_fp8(a1, BV, ACCN[1], 0, 0, 0);

#define STEP(S, B0, B1, B2, ACCARR)                                              \
    {                                                                            \
        const int ks_ = (S) < 4 ? (S) : (S) - 4;                                 \
        const long a0 = Xf8[(0 * 16 + ks_) * 64 + lane];                         \
        const long a1 = Xf8[(1 * 16 + ks_) * 64 + lane];                         \
        MFMA2(ACCARR[0], B0)                                                     \
        MFMA2(ACCARR[1], B1)                                                     \
        MFMA2(ACCARR[2], B2)                                                     \
    }                                                                            \
    if ((S) + 3 < 20) {                                                          \
        B0 = *WPTR(n0, (S) + 3);                                                 \
        B1 = *WPTR(n1, (S) + 3);                                                 \
        B2 = *WPTR(n2, (S) + 3);                                                 \
    }

__global__ __launch_bounds__(512, 4) void tgn_gru_fused(
    const float* __restrict__ mem, const int* __restrict__ head,
    const int* __restrict__ nxt,
    const int* __restrict__ src, const int* __restrict__ dst,
    const int* __restrict__ t, const float* __restrict__ raw_msg,
    const int* __restrict__ last_update,
    const float* __restrict__ time_w, const float* __restrict__ time_b,
    const long* __restrict__ Wb,
    const float* __restrict__ b_ih, const float* __restrict__ b_hh,
    const int* __restrict__ lu, float* __restrict__ out,
    float* __restrict__ out2, int n_nodes)
{
    __shared__ long   Xf8[2 * 16 * 64];     // 16 KB : X tile, fp8 frag-major
    __shared__ bf16x8 Mir[2 * 4 * 64];      //  8 KB : bf16 mirror of mem k-steps
    ushort* X16 = reinterpret_cast<ushort*>(Xf8);  // pair-writes in gather
    float*  Sout = reinterpret_cast<float*>(Xf8);  // 16 KB, reused after loop

    const int tid = threadIdx.x;
    const int lane = tid & 63;
    const int wv = tid >> 6;                 // wave id 0..7 (uniform)
    const int node0 = blockIdx.x * 32;

    const long* __restrict__ Wh = Wb + GI_SLOTS;
    const int n0 = wv, n1 = wv + 8, n2 = wv + 16;

    // ---- stage mem quarter of X (ks 0..3): f32 read -> fp8 + bf16 mirror ----
    {
        const int m = wv >> 2, ks = wv & 3;
        const int slotbase = (m * 16 + ks) * 64;
        int node = node0 + m * 16 + (lane & 15);
        if (node >= n_nodes) node = n_nodes - 1;
        const int kbase = ks * 32 + (lane >> 4) * 8;
        float v[8];
        const float4 pa = *reinterpret_cast<const float4*>(mem + (size_t)node * MEMD + kbase);
        const float4 pb = *reinterpret_cast<const float4*>(mem + (size_t)node * MEMD + kbase + 4);
        v[0] = pa.x; v[1] = pa.y; v[2] = pa.z; v[3] = pa.w;
        v[4] = pb.x; v[5] = pb.y; v[6] = pb.z; v[7] = pb.w;
        Xf8[slotbase + lane] = pack8fp8(v);
        bf16x8 xv;
        #pragma unroll
        for (int e = 0; e < 8; ++e) xv[e] = f2bf(v[e]);
        Mir[(m * 4 + ks) * 64 + lane] = xv;
    }

    // ---- ring prologue: weight steps 0,1,2 in flight ----
    long rA0 = *WPTR(n0, 0), rA1 = *WPTR(n1, 0), rA2 = *WPTR(n2, 0);
    long rB0 = *WPTR(n0, 1), rB1 = *WPTR(n1, 1), rB2 = *WPTR(n2, 1);
    long rC0 = *WPTR(n0, 2), rC1 = *WPTR(n1, 2), rC2 = *WPTR(n2, 2);

    const int col = lane & 15;
    const int rgrp = lane >> 4;

    // hmask early: loads overlap the gather's latency chains
    uint32_t hmask = 0;
    #pragma unroll
    for (int m = 0; m < 2; ++m)
        #pragma unroll
        for (int r = 0; r < 4; ++r) {
            const int node = node0 + m * 16 + rgrp * 4 + r;
            if (node < n_nodes && head[node] >= 0) hmask |= 1u << (m * 4 + r);
        }

    // ---- gather: 4 independent chains interleaved (4x MLP) ----
    {
        const int j0 = lane * 2;
        const float2 tw = *reinterpret_cast<const float2*>(time_w + j0);
        const float2 tb = *reinterpret_cast<const float2*>(time_b + j0);
        const int nb = node0 + wv * 4;

        int kq[4];
        float lus[4];
        float A[4][6];
        int C[4];
        #pragma unroll
        for (int q = 0; q < 4; ++q) {
            kq[q] = (nb + q < n_nodes) ? head[nb + q] : -1;
            lus[q] = 0.f;
            C[q] = 0;
            #pragma unroll
            for (int z = 0; z < 6; ++z) A[q][z] = 0.f;
        }
        #pragma unroll
        for (int q = 0; q < 4; ++q)
            if (kq[q] >= 0) lus[q] = (float)last_update[nb + q];

        bool more = (kq[0] >= 0) | (kq[1] >= 0) | (kq[2] >= 0) | (kq[3] >= 0);
        while (more) {
            #pragma unroll
            for (int q = 0; q < 4; ++q) {
                const int k = kq[q];
                if (k >= 0) {
                    kq[q] = nxt[k];
                    const int e = k >> 1;
                    const int other = (k & 1) ? src[e] : dst[e];
                    const float te = (float)t[e];
                    const float2 rw = *reinterpret_cast<const float2*>(raw_msg + (size_t)e * MEMD + j0);
                    const float2 mb = *reinterpret_cast<const float2*>(mem + (size_t)other * MEMD + j0);
                    const float dt = te - lus[q];
                    A[q][4] += __cosf(fmaf(dt, tw.x, tb.x));
                    A[q][5] += __cosf(fmaf(dt, tw.y, tb.y));
                    A[q][2] += rw.x; A[q][3] += rw.y;
                    A[q][0] += mb.x; A[q][1] += mb.y;
                    ++C[q];
                }
            }
            more = (kq[0] >= 0) | (kq[1] >= 0) | (kq[2] >= 0) | (kq[3] >= 0);
        }

        #pragma unroll
        for (int q = 0; q < 4; ++q) {
            if (C[q] > 0) {
                const float inv = 1.0f / (float)C[q];
                const int nn_ = wv * 4 + q;
                const int mn = nn_ >> 4, nif = nn_ & 15;
                #pragma unroll
                for (int p = 0; p < 3; ++p) {
                    const int cc = 128 + p * 128 + j0;       // X column of dim pair
                    const int ks = cc >> 5;
                    const int hi = (cc >> 3) & 3;
                    const int elem = cc & 7;                 // even
                    const int slot = (mn * 16 + ks) * 64 + hi * 16 + nif;
                    const uint32_t u0 = f2fp8(A[q][p * 2] * inv);
                    const uint32_t u1 = f2fp8(A[q][p * 2 + 1] * inv);
                    X16[slot * 4 + (elem >> 1)] = (ushort)(u0 | (u1 << 8));
                }
            }
        }
    }

    __syncthreads();   // X fully assembled; waves run free from here

    f32x4 acc_i[3][2], acc_h[3][2];
    #pragma unroll
    for (int c = 0; c < 3; ++c)
        #pragma unroll
        for (int m = 0; m < 2; ++m) {
            acc_i[c][m] = (f32x4){0.f, 0.f, 0.f, 0.f};
            acc_h[c][m] = (f32x4){0.f, 0.f, 0.f, 0.f};
        }

    // ---- 20 unified k-steps (gh 0..3 on Wh, gi 4..19 on Wb), ring ----
    STEP(0,  rA0, rA1, rA2, acc_h)
    STEP(1,  rB0, rB1, rB2, acc_h)
    STEP(2,  rC0, rC1, rC2, acc_h)
    STEP(3,  rA0, rA1, rA2, acc_h)
    STEP(4,  rB0, rB1, rB2, acc_i)
    STEP(5,  rC0, rC1, rC2, acc_i)
    STEP(6,  rA0, rA1, rA2, acc_i)
    STEP(7,  rB0, rB1, rB2, acc_i)
    STEP(8,  rC0, rC1, rC2, acc_i)
    STEP(9,  rA0, rA1, rA2, acc_i)
    STEP(10, rB0, rB1, rB2, acc_i)
    STEP(11, rC0, rC1, rC2, acc_i)
    STEP(12, rA0, rA1, rA2, acc_i)
    STEP(13, rB0, rB1, rB2, acc_i)
    STEP(14, rC0, rC1, rC2, acc_i)
    STEP(15, rA0, rA1, rA2, acc_i)
    STEP(16, rB0, rB1, rB2, acc_i)
    STEP(17, rC0, rC1, rC2, acc_i)
    STEP(18, rA0, rA1, rA2, acc_i)
    STEP(19, rB0, rB1, rB2, acc_i)

    // ---- GRU epilogue: wave-local triple (j, j+128, j+256) ----
    const int jr = wv * 16 + col;            // 0..127
    const float bir = b_ih[jr], biz = b_ih[jr + 128], bin = b_ih[jr + 256];
    const float bhr = b_hh[jr], bhz = b_hh[jr + 128], bhn = b_hh[jr + 256];
    const int ksj = jr >> 5;
    const int sub = ((jr >> 3) & 3) * 16;
    const int elem = jr & 7;
    ushort* MirH = reinterpret_cast<ushort*>(Mir);

    float rout[2][4];
    #pragma unroll
    for (int m = 0; m < 2; ++m) {
        #pragma unroll
        for (int r = 0; r < 4; ++r) {
            const bool has = (hmask >> (m * 4 + r)) & 1;
            const float gir = (has ? acc_i[0][m][r] : 0.f) + bir;
            const float giz = (has ? acc_i[1][m][r] : 0.f) + biz;
            const float gin = (has ? acc_i[2][m][r] : 0.f) + bin;
            const float ghr = acc_h[0][m][r] + bhr;
            const float ghz = acc_h[1][m][r] + bhz;
            const float ghn = acc_h[2][m][r] + bhn;
            const float rr = __fdividef(1.0f, 1.0f + __expf(-(gir + ghr)));
            const float zz = __fdividef(1.0f, 1.0f + __expf(-(giz + ghz)));
            const float targ = fmaf(rr, ghn, gin);
            const float e2v = __expf(2.0f * targ);
            const float nn = __fdividef(e2v - 1.0f, e2v + 1.0f);
            const int slot = (m * 4 + ksj) * 64 + sub + (rgrp * 4 + r);
            const float mv = bf2f((short)MirH[slot * 8 + elem]);
            rout[m][r] = (1.0f - zz) * nn + zz * mv;
        }
    }
    // fused last_update output (32 values per block)
    if (tid < 32 && node0 + tid < n_nodes) out2[node0 + tid] = (float)lu[node0 + tid];
    __syncthreads();   // all waves done with Xf8 (A-frags) -> reuse as Sout

    #pragma unroll
    for (int m = 0; m < 2; ++m)
        #pragma unroll
        for (int r = 0; r < 4; ++r)
            Sout[(m * 16 + rgrp * 4 + r) * MEMD + jr] = rout[m][r];
    __syncthreads();

    // ---- fully-coalesced float4 write-out (32 nodes x 128 f32) ----
    float4* out4 = reinterpret_cast<float4*>(out + (size_t)node0 * MEMD);
    const float4* S4 = reinterpret_cast<const float4*>(Sout);
    if (node0 + 32 <= n_nodes) {
        #pragma unroll
        for (int it = 0; it < 2; ++it)
            out4[it * 512 + tid] = S4[it * 512 + tid];
    } else {
        #pragma unroll
        for (int it = 0; it < 2; ++it) {
            const int idx = it * 512 + tid;
            if (node0 + (idx >> 5) < n_nodes) out4[idx] = S4[idx];
        }
    }
}

extern "C" void kernel_launch(void* const* d_in, const int* in_sizes, int n_in,
                              void* d_out, int out_size, void* d_ws, size_t ws_size,
                              hipStream_t stream)
{
    const float* memory      = (const float*)d_in[0];
    const int*   last_update = (const int*)d_in[1];
    const int*   src         = (const int*)d_in[2];
    const int*   dst         = (const int*)d_in[3];
    const int*   t           = (const int*)d_in[4];
    const float* raw_msg     = (const float*)d_in[5];
    const float* time_w      = (const float*)d_in[6];
    const float* time_b      = (const float*)d_in[7];
    const float* W_ih        = (const float*)d_in[8];
    const float* W_hh        = (const float*)d_in[9];
    const float* b_ih        = (const float*)d_in[10];
    const float* b_hh        = (const float*)d_in[11];

    const int n_nodes  = in_sizes[0] / MEMD;
    const int n_events = in_sizes[2];

    // Workspace: head | next | lu | Wb(fp8)
    int*   head = (int*)d_ws;
    int*   nxt  = head + n_nodes;
    int*   lu   = nxt + 2 * n_events;
    long*  Wb   = (long*)(lu + n_nodes);

    (void)hipMemsetAsync(head, 0xFF, (size_t)n_nodes * sizeof(int), stream); // -1
    (void)hipMemsetAsync(lu, 0, (size_t)n_nodes * sizeof(int), stream);

    tgn_prep_w<<<dim3((GI_SLOTS + GH_SLOTS + 255) / 256), dim3(256), 0, stream>>>(W_ih, W_hh, Wb);

    tgn_fill<<<dim3((n_events + 255) / 256), dim3(256), 0, stream>>>(
        src, dst, t, head, nxt, lu, n_events);

    float* out2 = (float*)d_out + (size_t)n_nodes * MEMD;
    tgn_gru_fused<<<dim3((n_nodes + 31) / 32), dim3(512), 0, stream>>>(
        memory, head, nxt, src, dst, t, raw_msg, last_update, time_w, time_b,
        Wb, b_ih, b_hh, lu, (float*)d_out, out2, n_nodes);
}

// Round 21
// 315.405 us; speedup vs baseline: 1.1593x; 1.0189x over previous
//
#include <hip/hip_runtime.h>
#include <cstdint>

// TGN memory update — round 21: R18 (best, 303.8us) + s_setprio(1) around
// the MFMA cluster (T5: waves are desynced/free-running here, the regime
// where setprio measured +4-7%). Everything else identical to R18.

#define MEMD 128
#define ACCD 384
#define MSGD 512

typedef __attribute__((ext_vector_type(8))) short bf16x8;
typedef __attribute__((ext_vector_type(2))) short bf16x2;
typedef __attribute__((ext_vector_type(4))) float f32x4;

static __device__ __forceinline__ short f2bf(float f) {
    uint32_t u = __builtin_bit_cast(uint32_t, f);
    u = (u + 0x7FFFu + ((u >> 16) & 1u)) >> 16;
    return (short)u;
}
static __device__ __forceinline__ float bf2f(short s) {
    return __builtin_bit_cast(float, ((uint32_t)(uint16_t)s) << 16);
}
static __device__ __forceinline__ uint32_t pack2bf(float a, float b) {
    return (uint32_t)(uint16_t)f2bf(a) | ((uint32_t)(uint16_t)f2bf(b) << 16);
}

// ---------------- Prep B: weights f32 -> bf16 frag-major ----------------
#define GI_SLOTS (24 * 16 * 64)
#define GH_SLOTS (24 * 4 * 64)

__global__ __launch_bounds__(256) void tgn_prep_w(
    const float* __restrict__ W_ih, const float* __restrict__ W_hh,
    bf16x8* __restrict__ Wb)
{
    const int s = blockIdx.x * 256 + threadIdx.x;
    if (s >= GI_SLOTS + GH_SLOTS) return;
    const float* src;
    if (s < GI_SLOTS) {
        const int n = s / (16 * 64), rem = s % (16 * 64);
        const int ks = rem / 64, l = rem % 64;
        const int j = n * 16 + (l & 15), k = ks * 32 + (l >> 4) * 8;
        src = W_ih + (size_t)j * MSGD + k;
    } else {
        const int s2 = s - GI_SLOTS;
        const int n = s2 / (4 * 64), rem = s2 % (4 * 64);
        const int ks = rem / 64, l = rem % 64;
        const int j = n * 16 + (l & 15), k = ks * 32 + (l >> 4) * 8;
        src = W_hh + (size_t)j * MEMD + k;
    }
    bf16x8 v;
    #pragma unroll
    for (int e = 0; e < 8; ++e) v[e] = f2bf(src[e]);
    Wb[s] = v;
}

// ---------------- Phase 1: build per-node linked lists ----------------
__global__ __launch_bounds__(256) void tgn_fill(
    const int* __restrict__ src, const int* __restrict__ dst, const int* __restrict__ t,
    int* __restrict__ head, int* __restrict__ nxt, int* __restrict__ lu_new,
    int n_events)
{
    const int e = blockIdx.x * 256 + threadIdx.x;
    if (e >= n_events) return;
    const int s = src[e];
    const int d = dst[e];
    const int te = t[e];
    nxt[2 * e]     = atomicExch(head + s, 2 * e);
    nxt[2 * e + 1] = atomicExch(head + d, 2 * e + 1);
    atomicMax(lu_new + s, te);
    atomicMax(lu_new + d, te);
}

// ---------------- Phase 2: fused gather + MFMA GEMM + GRU ----------------
// 512 threads (8 waves), 32 nodes/block. Wave wv: gathers nodes wv*4..+3
// (4 chains interleaved), owns N-tiles {wv, wv+8, wv+16}. e/o W prefetch.
#define WPTR(NN, S) ((S) < 4 ? (Wh + (size_t)((NN) * 4 + (S)) * 64 + lane)      \
                             : (Wb + (size_t)((NN) * 16 + (S) - 4) * 64 + lane))

#define MFMA2(ACCN, BV)                                                          \
    ACCN[0] = __builtin_amdgcn_mfma_f32_16x16x32_bf16(a0, BV, ACCN[0], 0, 0, 0); \
    ACCN[1] = __builtin_amdgcn_mfma_f32_16x16x32_bf16(a1, BV, ACCN[1], 0, 0, 0);

#define STEP(S, B0, B1, B2, ACCARR)                                              \
    {                                                                            \
        const int ks_ = (S) < 4 ? (S) : (S) - 4;                                 \
        const bf16x8 a0 = Xf[(0 * 16 + ks_) * 64 + lane];                        \
        const bf16x8 a1 = Xf[(1 * 16 + ks_) * 64 + lane];                        \
        __builtin_amdgcn_s_setprio(1);                                           \
        MFMA2(ACCARR[0], B0)                                                     \
        MFMA2(ACCARR[1], B1)                                                     \
        MFMA2(ACCARR[2], B2)                                                     \
        __builtin_amdgcn_s_setprio(0);                                           \
    }                                                                            \
    if ((S) + 3 < 20) {                                                          \
        B0 = *WPTR(n0, (S) + 3);                                                 \
        B1 = *WPTR(n1, (S) + 3);                                                 \
        B2 = *WPTR(n2, (S) + 3);                                                 \
    }

__global__ __launch_bounds__(512, 4) void tgn_gru_fused(
    const float* __restrict__ mem, const int* __restrict__ head,
    const int* __restrict__ nxt,
    const int* __restrict__ src, const int* __restrict__ dst,
    const int* __restrict__ t, const float* __restrict__ raw_msg,
    const int* __restrict__ last_update,
    const float* __restrict__ time_w, const float* __restrict__ time_b,
    const bf16x8* __restrict__ Wb,
    const float* __restrict__ b_ih, const float* __restrict__ b_hh,
    const int* __restrict__ lu, float* __restrict__ out,
    float* __restrict__ out2, int n_nodes)
{
    __shared__ bf16x8 Xf[2 * 16 * 64];      // 32 KB : X tile (frag-major)
    ushort* Xh = reinterpret_cast<ushort*>(Xf);
    uint32_t* X32 = reinterpret_cast<uint32_t*>(Xf);
    float*  Sout = reinterpret_cast<float*>(Xf);   // reused after mv reads

    const int tid = threadIdx.x;
    const int lane = tid & 63;
    const int wv = tid >> 6;                 // wave id 0..7 (uniform)
    const int node0 = blockIdx.x * 32;

    const bf16x8* __restrict__ Wh = Wb + GI_SLOTS;
    const int n0 = wv, n1 = wv + 8, n2 = wv + 16;

    // ---- stage mem quarter of X (ks 0..3): direct f32 read + convert ----
    {
        const int m = wv >> 2, ks = wv & 3;
        const int slotbase = (m * 16 + ks) * 64;
        int node = node0 + m * 16 + (lane & 15);
        if (node >= n_nodes) node = n_nodes - 1;
        const int kbase = ks * 32 + (lane >> 4) * 8;
        const float4 pa = *reinterpret_cast<const float4*>(mem + (size_t)node * MEMD + kbase);
        const float4 pb = *reinterpret_cast<const float4*>(mem + (size_t)node * MEMD + kbase + 4);
        bf16x8 xv;
        xv[0] = f2bf(pa.x); xv[1] = f2bf(pa.y); xv[2] = f2bf(pa.z); xv[3] = f2bf(pa.w);
        xv[4] = f2bf(pb.x); xv[5] = f2bf(pb.y); xv[6] = f2bf(pb.z); xv[7] = f2bf(pb.w);
        Xf[slotbase + lane] = xv;
    }

    // ---- ring prologue: weight steps 0,1,2 in flight ----
    bf16x8 rA0 = *WPTR(n0, 0), rA1 = *WPTR(n1, 0), rA2 = *WPTR(n2, 0);
    bf16x8 rB0 = *WPTR(n0, 1), rB1 = *WPTR(n1, 1), rB2 = *WPTR(n2, 1);
    bf16x8 rC0 = *WPTR(n0, 2), rC1 = *WPTR(n1, 2), rC2 = *WPTR(n2, 2);

    const int col = lane & 15;
    const int rgrp = lane >> 4;

    // hmask early: loads overlap the gather's latency chains
    uint32_t hmask = 0;
    #pragma unroll
    for (int m = 0; m < 2; ++m)
        #pragma unroll
        for (int r = 0; r < 4; ++r) {
            const int node = node0 + m * 16 + rgrp * 4 + r;
            if (node < n_nodes && head[node] >= 0) hmask |= 1u << (m * 4 + r);
        }

    // ---- gather: 4 independent chains interleaved (4x MLP) ----
    {
        const int j0 = lane * 2;
        const float2 tw = *reinterpret_cast<const float2*>(time_w + j0);
        const float2 tb = *reinterpret_cast<const float2*>(time_b + j0);
        const int nb = node0 + wv * 4;

        int kq[4];
        float lus[4];
        float A[4][6];
        int C[4];
        #pragma unroll
        for (int q = 0; q < 4; ++q) {
            kq[q] = (nb + q < n_nodes) ? head[nb + q] : -1;
            lus[q] = 0.f;
            C[q] = 0;
            #pragma unroll
            for (int z = 0; z < 6; ++z) A[q][z] = 0.f;
        }
        #pragma unroll
        for (int q = 0; q < 4; ++q)
            if (kq[q] >= 0) lus[q] = (float)last_update[nb + q];

        bool more = (kq[0] >= 0) | (kq[1] >= 0) | (kq[2] >= 0) | (kq[3] >= 0);
        while (more) {
            #pragma unroll
            for (int q = 0; q < 4; ++q) {
                const int k = kq[q];
                if (k >= 0) {
                    kq[q] = nxt[k];
                    const int e = k >> 1;
                    const int other = (k & 1) ? src[e] : dst[e];
                    const float te = (float)t[e];
                    const float2 rw = *reinterpret_cast<const float2*>(raw_msg + (size_t)e * MEMD + j0);
                    const float2 mb = *reinterpret_cast<const float2*>(mem + (size_t)other * MEMD + j0);
                    const float dt = te - lus[q];
                    A[q][4] += __cosf(fmaf(dt, tw.x, tb.x));
                    A[q][5] += __cosf(fmaf(dt, tw.y, tb.y));
                    A[q][2] += rw.x; A[q][3] += rw.y;
                    A[q][0] += mb.x; A[q][1] += mb.y;
                    ++C[q];
                }
            }
            more = (kq[0] >= 0) | (kq[1] >= 0) | (kq[2] >= 0) | (kq[3] >= 0);
        }

        #pragma unroll
        for (int q = 0; q < 4; ++q) {
            if (C[q] > 0) {
                const float inv = 1.0f / (float)C[q];
                const int nn_ = wv * 4 + q;
                const int mn = nn_ >> 4, nif = nn_ & 15;
                #pragma unroll
                for (int p = 0; p < 3; ++p) {
                    const int cc = 128 + p * 128 + j0;       // X column of dim pair
                    const int ks = cc >> 5;
                    const int hi = (cc >> 3) & 3;
                    const int u32idx = ((mn * 16 + ks) * 64 + hi * 16 + nif) * 4 + (lane & 3);
                    X32[u32idx] = pack2bf(A[q][p * 2] * inv, A[q][p * 2 + 1] * inv);
                }
            }
        }
    }

    __syncthreads();   // X fully assembled; waves run free from here

    f32x4 acc_i[3][2], acc_h[3][2];
    #pragma unroll
    for (int c = 0; c < 3; ++c)
        #pragma unroll
        for (int m = 0; m < 2; ++m) {
            acc_i[c][m] = (f32x4){0.f, 0.f, 0.f, 0.f};
            acc_h[c][m] = (f32x4){0.f, 0.f, 0.f, 0.f};
        }

    // ---- 20 unified k-steps (gh 0..3 on Wh, gi 4..19 on Wb), ring ----
    STEP(0,  rA0, rA1, rA2, acc_h)
    STEP(1,  rB0, rB1, rB2, acc_h)
    STEP(2,  rC0, rC1, rC2, acc_h)
    STEP(3,  rA0, rA1, rA2, acc_h)
    STEP(4,  rB0, rB1, rB2, acc_i)
    STEP(5,  rC0, rC1, rC2, acc_i)
    STEP(6,  rA0, rA1, rA2, acc_i)
    STEP(7,  rB0, rB1, rB2, acc_i)
    STEP(8,  rC0, rC1, rC2, acc_i)
    STEP(9,  rA0, rA1, rA2, acc_i)
    STEP(10, rB0, rB1, rB2, acc_i)
    STEP(11, rC0, rC1, rC2, acc_i)
    STEP(12, rA0, rA1, rA2, acc_i)
    STEP(13, rB0, rB1, rB2, acc_i)
    STEP(14, rC0, rC1, rC2, acc_i)
    STEP(15, rA0, rA1, rA2, acc_i)
    STEP(16, rB0, rB1, rB2, acc_i)
    STEP(17, rC0, rC1, rC2, acc_i)
    STEP(18, rA0, rA1, rA2, acc_i)
    STEP(19, rB0, rB1, rB2, acc_i)

    // ---- GRU epilogue: wave-local triple (j, j+128, j+256) ----
    const int jr = wv * 16 + col;            // 0..127
    const float bir = b_ih[jr], biz = b_ih[jr + 128], bin = b_ih[jr + 256];
    const float bhr = b_hh[jr], bhz = b_hh[jr + 128], bhn = b_hh[jr + 256];
    const int ksj = jr >> 5;
    const int sub = ((jr >> 3) & 3) * 16;
    const int elem = jr & 7;

    float rout[2][4];
    #pragma unroll
    for (int m = 0; m < 2; ++m) {
        #pragma unroll
        for (int r = 0; r < 4; ++r) {
            const bool has = (hmask >> (m * 4 + r)) & 1;
            const float gir = (has ? acc_i[0][m][r] : 0.f) + bir;
            const float giz = (has ? acc_i[1][m][r] : 0.f) + biz;
            const float gin = (has ? acc_i[2][m][r] : 0.f) + bin;
            const float ghr = acc_h[0][m][r] + bhr;
            const float ghz = acc_h[1][m][r] + bhz;
            const float ghn = acc_h[2][m][r] + bhn;
            const float rr = __fdividef(1.0f, 1.0f + __expf(-(gir + ghr)));
            const float zz = __fdividef(1.0f, 1.0f + __expf(-(giz + ghz)));
            const float targ = fmaf(rr, ghn, gin);
            const float e2v = __expf(2.0f * targ);
            const float nn = __fdividef(e2v - 1.0f, e2v + 1.0f);
            const int slot = (m * 16 + ksj) * 64 + sub + (rgrp * 4 + r);
            const float mv = bf2f((short)Xh[slot * 8 + elem]);
            rout[m][r] = (1.0f - zz) * nn + zz * mv;
        }
    }
    // fused last_update output (32 values per block)
    if (tid < 32 && node0 + tid < n_nodes) out2[node0 + tid] = (float)lu[node0 + tid];
    __syncthreads();   // all waves done with Xf (mv) -> reuse as Sout

    #pragma unroll
    for (int m = 0; m < 2; ++m)
        #pragma unroll
        for (int r = 0; r < 4; ++r)
            Sout[(m * 16 + rgrp * 4 + r) * MEMD + jr] = rout[m][r];
    __syncthreads();

    // ---- fully-coalesced float4 write-out (32 nodes x 128 f32) ----
    float4* out4 = reinterpret_cast<float4*>(out + (size_t)node0 * MEMD);
    const float4* S4 = reinterpret_cast<const float4*>(Sout);
    if (node0 + 32 <= n_nodes) {
        #pragma unroll
        for (int it = 0; it < 2; ++it)
            out4[it * 512 + tid] = S4[it * 512 + tid];
    } else {
        #pragma unroll
        for (int it = 0; it < 2; ++it) {
            const int idx = it * 512 + tid;
            if (node0 + (idx >> 5) < n_nodes) out4[idx] = S4[idx];
        }
    }
}

extern "C" void kernel_launch(void* const* d_in, const int* in_sizes, int n_in,
                              void* d_out, int out_size, void* d_ws, size_t ws_size,
                              hipStream_t stream)
{
    const float* memory      = (const float*)d_in[0];
    const int*   last_update = (const int*)d_in[1];
    const int*   src         = (const int*)d_in[2];
    const int*   dst         = (const int*)d_in[3];
    const int*   t           = (const int*)d_in[4];
    const float* raw_msg     = (const float*)d_in[5];
    const float* time_w      = (const float*)d_in[6];
    const float* time_b      = (const float*)d_in[7];
    const float* W_ih        = (const float*)d_in[8];
    const float* W_hh        = (const float*)d_in[9];
    const float* b_ih        = (const float*)d_in[10];
    const float* b_hh        = (const float*)d_in[11];

    const int n_nodes  = in_sizes[0] / MEMD;
    const int n_events = in_sizes[2];

    // Workspace: head | next | lu | Wb
    int*   head = (int*)d_ws;
    int*   nxt  = head + n_nodes;
    int*   lu   = nxt + 2 * n_events;
    bf16x8* Wb  = (bf16x8*)(lu + n_nodes);

    (void)hipMemsetAsync(head, 0xFF, (size_t)n_nodes * sizeof(int), stream); // -1
    (void)hipMemsetAsync(lu, 0, (size_t)n_nodes * sizeof(int), stream);

    tgn_prep_w<<<dim3((GI_SLOTS + GH_SLOTS + 255) / 256), dim3(256), 0, stream>>>(W_ih, W_hh, Wb);

    tgn_fill<<<dim3((n_events + 255) / 256), dim3(256), 0, stream>>>(
        src, dst, t, head, nxt, lu, n_events);

    float* out2 = (float*)d_out + (size_t)n_nodes * MEMD;
    tgn_gru_fused<<<dim3((n_nodes + 31) / 32), dim3(512), 0, stream>>>(
        memory, head, nxt, src, dst, t, raw_msg, last_update, time_w, time_b,
        Wb, b_ih, b_hh, lu, (float*)d_out, out2, n_nodes);
}

// Round 22
// 303.091 us; speedup vs baseline: 1.2064x; 1.0406x over previous
//
#include <hip/hip_runtime.h>
#include <cstdint>

// TGN memory update — round 22: exact revert to R18 (best: 303.8 us).
// Fused gather (linked-list, 4-chain MLP) + bf16 MFMA GEMM (M=32, 8 waves,
// depth-3 reg ring declaration, no loop barriers) + GRU epilogue.

#define MEMD 128
#define ACCD 384
#define MSGD 512

typedef __attribute__((ext_vector_type(8))) short bf16x8;
typedef __attribute__((ext_vector_type(2))) short bf16x2;
typedef __attribute__((ext_vector_type(4))) float f32x4;

static __device__ __forceinline__ short f2bf(float f) {
    uint32_t u = __builtin_bit_cast(uint32_t, f);
    u = (u + 0x7FFFu + ((u >> 16) & 1u)) >> 16;
    return (short)u;
}
static __device__ __forceinline__ float bf2f(short s) {
    return __builtin_bit_cast(float, ((uint32_t)(uint16_t)s) << 16);
}
static __device__ __forceinline__ uint32_t pack2bf(float a, float b) {
    return (uint32_t)(uint16_t)f2bf(a) | ((uint32_t)(uint16_t)f2bf(b) << 16);
}

// ---------------- Prep B: weights f32 -> bf16 frag-major ----------------
#define GI_SLOTS (24 * 16 * 64)
#define GH_SLOTS (24 * 4 * 64)

__global__ __launch_bounds__(256) void tgn_prep_w(
    const float* __restrict__ W_ih, const float* __restrict__ W_hh,
    bf16x8* __restrict__ Wb)
{
    const int s = blockIdx.x * 256 + threadIdx.x;
    if (s >= GI_SLOTS + GH_SLOTS) return;
    const float* src;
    if (s < GI_SLOTS) {
        const int n = s / (16 * 64), rem = s % (16 * 64);
        const int ks = rem / 64, l = rem % 64;
        const int j = n * 16 + (l & 15), k = ks * 32 + (l >> 4) * 8;
        src = W_ih + (size_t)j * MSGD + k;
    } else {
        const int s2 = s - GI_SLOTS;
        const int n = s2 / (4 * 64), rem = s2 % (4 * 64);
        const int ks = rem / 64, l = rem % 64;
        const int j = n * 16 + (l & 15), k = ks * 32 + (l >> 4) * 8;
        src = W_hh + (size_t)j * MEMD + k;
    }
    bf16x8 v;
    #pragma unroll
    for (int e = 0; e < 8; ++e) v[e] = f2bf(src[e]);
    Wb[s] = v;
}

// ---------------- Phase 1: build per-node linked lists ----------------
__global__ __launch_bounds__(256) void tgn_fill(
    const int* __restrict__ src, const int* __restrict__ dst, const int* __restrict__ t,
    int* __restrict__ head, int* __restrict__ nxt, int* __restrict__ lu_new,
    int n_events)
{
    const int e = blockIdx.x * 256 + threadIdx.x;
    if (e >= n_events) return;
    const int s = src[e];
    const int d = dst[e];
    const int te = t[e];
    nxt[2 * e]     = atomicExch(head + s, 2 * e);
    nxt[2 * e + 1] = atomicExch(head + d, 2 * e + 1);
    atomicMax(lu_new + s, te);
    atomicMax(lu_new + d, te);
}

// ---------------- Phase 2: fused gather + MFMA GEMM + GRU ----------------
// 512 threads (8 waves), 32 nodes/block. Wave wv: gathers nodes wv*4..+3
// (4 chains interleaved), owns N-tiles {wv, wv+8, wv+16}. Depth-3 reg ring.
#define WPTR(NN, S) ((S) < 4 ? (Wh + (size_t)((NN) * 4 + (S)) * 64 + lane)      \
                             : (Wb + (size_t)((NN) * 16 + (S) - 4) * 64 + lane))

#define MFMA2(ACCN, BV)                                                          \
    ACCN[0] = __builtin_amdgcn_mfma_f32_16x16x32_bf16(a0, BV, ACCN[0], 0, 0, 0); \
    ACCN[1] = __builtin_amdgcn_mfma_f32_16x16x32_bf16(a1, BV, ACCN[1], 0, 0, 0);

#define STEP(S, B0, B1, B2, ACCARR)                                              \
    {                                                                            \
        const int ks_ = (S) < 4 ? (S) : (S) - 4;                                 \
        const bf16x8 a0 = Xf[(0 * 16 + ks_) * 64 + lane];                        \
        const bf16x8 a1 = Xf[(1 * 16 + ks_) * 64 + lane];                        \
        MFMA2(ACCARR[0], B0)                                                     \
        MFMA2(ACCARR[1], B1)                                                     \
        MFMA2(ACCARR[2], B2)                                                     \
    }                                                                            \
    if ((S) + 3 < 20) {                                                          \
        B0 = *WPTR(n0, (S) + 3);                                                 \
        B1 = *WPTR(n1, (S) + 3);                                                 \
        B2 = *WPTR(n2, (S) + 3);                                                 \
    }

__global__ __launch_bounds__(512, 4) void tgn_gru_fused(
    const float* __restrict__ mem, const int* __restrict__ head,
    const int* __restrict__ nxt,
    const int* __restrict__ src, const int* __restrict__ dst,
    const int* __restrict__ t, const float* __restrict__ raw_msg,
    const int* __restrict__ last_update,
    const float* __restrict__ time_w, const float* __restrict__ time_b,
    const bf16x8* __restrict__ Wb,
    const float* __restrict__ b_ih, const float* __restrict__ b_hh,
    const int* __restrict__ lu, float* __restrict__ out,
    float* __restrict__ out2, int n_nodes)
{
    __shared__ bf16x8 Xf[2 * 16 * 64];      // 32 KB : X tile (frag-major)
    ushort* Xh = reinterpret_cast<ushort*>(Xf);
    uint32_t* X32 = reinterpret_cast<uint32_t*>(Xf);
    float*  Sout = reinterpret_cast<float*>(Xf);   // reused after mv reads

    const int tid = threadIdx.x;
    const int lane = tid & 63;
    const int wv = tid >> 6;                 // wave id 0..7 (uniform)
    const int node0 = blockIdx.x * 32;

    const bf16x8* __restrict__ Wh = Wb + GI_SLOTS;
    const int n0 = wv, n1 = wv + 8, n2 = wv + 16;

    // ---- stage mem quarter of X (ks 0..3): direct f32 read + convert ----
    {
        const int m = wv >> 2, ks = wv & 3;
        const int slotbase = (m * 16 + ks) * 64;
        int node = node0 + m * 16 + (lane & 15);
        if (node >= n_nodes) node = n_nodes - 1;
        const int kbase = ks * 32 + (lane >> 4) * 8;
        const float4 pa = *reinterpret_cast<const float4*>(mem + (size_t)node * MEMD + kbase);
        const float4 pb = *reinterpret_cast<const float4*>(mem + (size_t)node * MEMD + kbase + 4);
        bf16x8 xv;
        xv[0] = f2bf(pa.x); xv[1] = f2bf(pa.y); xv[2] = f2bf(pa.z); xv[3] = f2bf(pa.w);
        xv[4] = f2bf(pb.x); xv[5] = f2bf(pb.y); xv[6] = f2bf(pb.z); xv[7] = f2bf(pb.w);
        Xf[slotbase + lane] = xv;
    }

    // ---- ring prologue: weight steps 0,1,2 in flight ----
    bf16x8 rA0 = *WPTR(n0, 0), rA1 = *WPTR(n1, 0), rA2 = *WPTR(n2, 0);
    bf16x8 rB0 = *WPTR(n0, 1), rB1 = *WPTR(n1, 1), rB2 = *WPTR(n2, 1);
    bf16x8 rC0 = *WPTR(n0, 2), rC1 = *WPTR(n1, 2), rC2 = *WPTR(n2, 2);

    const int col = lane & 15;
    const int rgrp = lane >> 4;

    // hmask early: loads overlap the gather's latency chains
    uint32_t hmask = 0;
    #pragma unroll
    for (int m = 0; m < 2; ++m)
        #pragma unroll
        for (int r = 0; r < 4; ++r) {
            const int node = node0 + m * 16 + rgrp * 4 + r;
            if (node < n_nodes && head[node] >= 0) hmask |= 1u << (m * 4 + r);
        }

    // ---- gather: 4 independent chains interleaved (4x MLP) ----
    {
        const int j0 = lane * 2;
        const float2 tw = *reinterpret_cast<const float2*>(time_w + j0);
        const float2 tb = *reinterpret_cast<const float2*>(time_b + j0);
        const int nb = node0 + wv * 4;

        int kq[4];
        float lus[4];
        float A[4][6];
        int C[4];
        #pragma unroll
        for (int q = 0; q < 4; ++q) {
            kq[q] = (nb + q < n_nodes) ? head[nb + q] : -1;
            lus[q] = 0.f;
            C[q] = 0;
            #pragma unroll
            for (int z = 0; z < 6; ++z) A[q][z] = 0.f;
        }
        #pragma unroll
        for (int q = 0; q < 4; ++q)
            if (kq[q] >= 0) lus[q] = (float)last_update[nb + q];

        bool more = (kq[0] >= 0) | (kq[1] >= 0) | (kq[2] >= 0) | (kq[3] >= 0);
        while (more) {
            #pragma unroll
            for (int q = 0; q < 4; ++q) {
                const int k = kq[q];
                if (k >= 0) {
                    kq[q] = nxt[k];
                    const int e = k >> 1;
                    const int other = (k & 1) ? src[e] : dst[e];
                    const float te = (float)t[e];
                    const float2 rw = *reinterpret_cast<const float2*>(raw_msg + (size_t)e * MEMD + j0);
                    const float2 mb = *reinterpret_cast<const float2*>(mem + (size_t)other * MEMD + j0);
                    const float dt = te - lus[q];
                    A[q][4] += __cosf(fmaf(dt, tw.x, tb.x));
                    A[q][5] += __cosf(fmaf(dt, tw.y, tb.y));
                    A[q][2] += rw.x; A[q][3] += rw.y;
                    A[q][0] += mb.x; A[q][1] += mb.y;
                    ++C[q];
                }
            }
            more = (kq[0] >= 0) | (kq[1] >= 0) | (kq[2] >= 0) | (kq[3] >= 0);
        }

        #pragma unroll
        for (int q = 0; q < 4; ++q) {
            if (C[q] > 0) {
                const float inv = 1.0f / (float)C[q];
                const int nn_ = wv * 4 + q;
                const int mn = nn_ >> 4, nif = nn_ & 15;
                #pragma unroll
                for (int p = 0; p < 3; ++p) {
                    const int cc = 128 + p * 128 + j0;       // X column of dim pair
                    const int ks = cc >> 5;
                    const int hi = (cc >> 3) & 3;
                    const int u32idx = ((mn * 16 + ks) * 64 + hi * 16 + nif) * 4 + (lane & 3);
                    X32[u32idx] = pack2bf(A[q][p * 2] * inv, A[q][p * 2 + 1] * inv);
                }
            }
        }
    }

    __syncthreads();   // X fully assembled; waves run free from here

    f32x4 acc_i[3][2], acc_h[3][2];
    #pragma unroll
    for (int c = 0; c < 3; ++c)
        #pragma unroll
        for (int m = 0; m < 2; ++m) {
            acc_i[c][m] = (f32x4){0.f, 0.f, 0.f, 0.f};
            acc_h[c][m] = (f32x4){0.f, 0.f, 0.f, 0.f};
        }

    // ---- 20 unified k-steps (gh 0..3 on Wh, gi 4..19 on Wb), ring ----
    STEP(0,  rA0, rA1, rA2, acc_h)
    STEP(1,  rB0, rB1, rB2, acc_h)
    STEP(2,  rC0, rC1, rC2, acc_h)
    STEP(3,  rA0, rA1, rA2, acc_h)
    STEP(4,  rB0, rB1, rB2, acc_i)
    STEP(5,  rC0, rC1, rC2, acc_i)
    STEP(6,  rA0, rA1, rA2, acc_i)
    STEP(7,  rB0, rB1, rB2, acc_i)
    STEP(8,  rC0, rC1, rC2, acc_i)
    STEP(9,  rA0, rA1, rA2, acc_i)
    STEP(10, rB0, rB1, rB2, acc_i)
    STEP(11, rC0, rC1, rC2, acc_i)
    STEP(12, rA0, rA1, rA2, acc_i)
    STEP(13, rB0, rB1, rB2, acc_i)
    STEP(14, rC0, rC1, rC2, acc_i)
    STEP(15, rA0, rA1, rA2, acc_i)
    STEP(16, rB0, rB1, rB2, acc_i)
    STEP(17, rC0, rC1, rC2, acc_i)
    STEP(18, rA0, rA1, rA2, acc_i)
    STEP(19, rB0, rB1, rB2, acc_i)

    // ---- GRU epilogue: wave-local triple (j, j+128, j+256) ----
    const int jr = wv * 16 + col;            // 0..127
    const float bir = b_ih[jr], biz = b_ih[jr + 128], bin = b_ih[jr + 256];
    const float bhr = b_hh[jr], bhz = b_hh[jr + 128], bhn = b_hh[jr + 256];
    const int ksj = jr >> 5;
    const int sub = ((jr >> 3) & 3) * 16;
    const int elem = jr & 7;

    float rout[2][4];
    #pragma unroll
    for (int m = 0; m < 2; ++m) {
        #pragma unroll
        for (int r = 0; r < 4; ++r) {
            const bool has = (hmask >> (m * 4 + r)) & 1;
            const float gir = (has ? acc_i[0][m][r] : 0.f) + bir;
            const float giz = (has ? acc_i[1][m][r] : 0.f) + biz;
            const float gin = (has ? acc_i[2][m][r] : 0.f) + bin;
            const float ghr = acc_h[0][m][r] + bhr;
            const float ghz = acc_h[1][m][r] + bhz;
            const float ghn = acc_h[2][m][r] + bhn;
            const float rr = __fdividef(1.0f, 1.0f + __expf(-(gir + ghr)));
            const float zz = __fdividef(1.0f, 1.0f + __expf(-(giz + ghz)));
            const float targ = fmaf(rr, ghn, gin);
            const float e2v = __expf(2.0f * targ);
            const float nn = __fdividef(e2v - 1.0f, e2v + 1.0f);
            const int slot = (m * 16 + ksj) * 64 + sub + (rgrp * 4 + r);
            const float mv = bf2f((short)Xh[slot * 8 + elem]);
            rout[m][r] = (1.0f - zz) * nn + zz * mv;
        }
    }
    // fused last_update output (32 values per block)
    if (tid < 32 && node0 + tid < n_nodes) out2[node0 + tid] = (float)lu[node0 + tid];
    __syncthreads();   // all waves done with Xf (mv) -> reuse as Sout

    #pragma unroll
    for (int m = 0; m < 2; ++m)
        #pragma unroll
        for (int r = 0; r < 4; ++r)
            Sout[(m * 16 + rgrp * 4 + r) * MEMD + jr] = rout[m][r];
    __syncthreads();

    // ---- fully-coalesced float4 write-out (32 nodes x 128 f32) ----
    float4* out4 = reinterpret_cast<float4*>(out + (size_t)node0 * MEMD);
    const float4* S4 = reinterpret_cast<const float4*>(Sout);
    if (node0 + 32 <= n_nodes) {
        #pragma unroll
        for (int it = 0; it < 2; ++it)
            out4[it * 512 + tid] = S4[it * 512 + tid];
    } else {
        #pragma unroll
        for (int it = 0; it < 2; ++it) {
            const int idx = it * 512 + tid;
            if (node0 + (idx >> 5) < n_nodes) out4[idx] = S4[idx];
        }
    }
}

extern "C" void kernel_launch(void* const* d_in, const int* in_sizes, int n_in,
                              void* d_out, int out_size, void* d_ws, size_t ws_size,
                              hipStream_t stream)
{
    const float* memory      = (const float*)d_in[0];
    const int*   last_update = (const int*)d_in[1];
    const int*   src         = (const int*)d_in[2];
    const int*   dst         = (const int*)d_in[3];
    const int*   t           = (const int*)d_in[4];
    const float* raw_msg     = (const float*)d_in[5];
    const float* time_w      = (const float*)d_in[6];
    const float* time_b      = (const float*)d_in[7];
    const float* W_ih        = (const float*)d_in[8];
    const float* W_hh        = (const float*)d_in[9];
    const float* b_ih        = (const float*)d_in[10];
    const float* b_hh        = (const float*)d_in[11];

    const int n_nodes  = in_sizes[0] / MEMD;
    const int n_events = in_sizes[2];

    // Workspace: head | next | lu | Wb
    int*   head = (int*)d_ws;
    int*   nxt  = head + n_nodes;
    int*   lu   = nxt + 2 * n_events;
    bf16x8* Wb  = (bf16x8*)(lu + n_nodes);

    (void)hipMemsetAsync(head, 0xFF, (size_t)n_nodes * sizeof(int), stream); // -1
    (void)hipMemsetAsync(lu, 0, (size_t)n_nodes * sizeof(int), stream);

    tgn_prep_w<<<dim3((GI_SLOTS + GH_SLOTS + 255) / 256), dim3(256), 0, stream>>>(W_ih, W_hh, Wb);

    tgn_fill<<<dim3((n_events + 255) / 256), dim3(256), 0, stream>>>(
        src, dst, t, head, nxt, lu, n_events);

    float* out2 = (float*)d_out + (size_t)n_nodes * MEMD;
    tgn_gru_fused<<<dim3((n_nodes + 31) / 32), dim3(512), 0, stream>>>(
        memory, head, nxt, src, dst, t, raw_msg, last_update, time_w, time_b,
        Wb, b_ih, b_hh, lu, (float*)d_out, out2, n_nodes);
}